// Round 2
// baseline (8451.442 us; speedup 1.0000x reference)
//
#include <hip/hip_runtime.h>
#include <stdint.h>

typedef __bf16 bf16;
typedef __attribute__((ext_vector_type(8))) __bf16 bf16x8;
typedef __attribute__((ext_vector_type(4))) float f32x4;

// ---------------- workspace layout (bytes) ----------------
//   W0P: [tile 256][kt 40][lane 64][8 bf16]   (K=1280: x rows 0..255, h0 rows 256..1279)
//   W1P: [tile 256][kt 64][lane 64][8 bf16]   (K=2048: h0 rows 0..1023, h1 rows 1024..2047)
//   WOUT:[kt 32][nt 16][lane 64][8 bf16]      (K=1024, N=256)
//   XP:  [t 512][mt 4][kt 8][lane 64][8 bf16] (x repacked into A-frag order, always bf16)
//   FLAGS: 256 x u32 per-CU arrival flags (all-poll barrier)
#define OFF_W0P   0ull
#define SZ_W0P    10485760ull
#define OFF_W1P   (OFF_W0P + SZ_W0P)
#define SZ_W1P    16777216ull
#define OFF_WOUT  (OFF_W1P + SZ_W1P)
#define SZ_WOUT   524288ull
#define OFF_B0P   (OFF_WOUT + SZ_WOUT)      // f32 permuted b0 [4096]
#define OFF_B1P   (OFF_B0P + 16384ull)      // f32 permuted b1 [4096]
#define OFF_BOP   (OFF_B1P + 16384ull)      // f32 bout [256]
#define OFF_BAR   (OFF_BOP + 1024ull)       // (legacy, unused)
#define OFF_FLAG  (OFF_BAR + 128ull)        // dtype flag: 1 = inputs are f32, 0 = bf16
#define OFF_H0PP  (OFF_BAR + 256ull)        // h0 ping-pong: 2 x 131072 (A-frag packed bf16)
#define OFF_H1PP  (OFF_H0PP + 262144ull)    // h1 ping-pong: 2 x 131072
#define OFF_XP    (OFF_H1PP + 262144ull)
#define SZ_XP     16777216ull
#define OFF_FLAGS (OFF_XP + SZ_XP)          // 256 x u32 arrival flags (1 KB)
#define OFF_REL   (OFF_FLAGS + 1024ull)     // (unused this round)
// end = 45,123,968 bytes

#define OUT_FS0   8388608                   // final_state fs0 base (elements in d_out)
#define OUT_FS1   8519680                   // fs1 base

typedef const __attribute__((address_space(1))) void gvoid_t;
typedef __attribute__((address_space(3))) void lvoid_t;

__device__ __forceinline__ void gl_lds16(void* lds, const void* g) {
  __builtin_amdgcn_global_load_lds((gvoid_t*)g, (lvoid_t*)lds, 16, 0, 0);
}

// packed A-fragment byte offset for h buffers: element (batch b, unit u)
__device__ __forceinline__ size_t hpack_off(int b, int u) {
  return (size_t)((((b >> 4) * 32 + (u >> 5)) * 64 + ((b & 15) | (((u >> 3) & 3) << 4))) * 16 + ((u & 7) << 1));
}

__device__ __forceinline__ float sigm(float v) { return 1.0f / (1.0f + __expf(-v)); }
__device__ __forceinline__ float tanh_(float v) { return 2.0f / (1.0f + __expf(-2.0f * v)) - 1.0f; }
__device__ __forceinline__ float scrub(float v, float lim) { return fminf(fmaxf(v, -lim), lim); }

__device__ __forceinline__ float ldel(const void* p, size_t i, int fl) {
  return fl ? ((const float*)p)[i] : (float)((const bf16*)p)[i];
}

// ---------------- dtype detection ----------------
__global__ __launch_bounds__(256) void detect_kernel(const void* __restrict__ W0, char* __restrict__ ws) {
  __shared__ int cnt;
  if (threadIdx.x == 0) cnt = 0;
  __syncthreads();
  int local = 0;
  const unsigned* w = (const unsigned*)W0;
#pragma unroll
  for (int i = 0; i < 4; ++i) {
    unsigned e = (w[threadIdx.x * 4 + i] >> 7) & 0xFF;
    local += (e >= 0x68 && e <= 0x7E) ? 1 : 0;
  }
  atomicAdd(&cnt, local);
  __syncthreads();
  if (threadIdx.x == 0) *(unsigned*)(ws + OFF_FLAG) = (cnt < 512) ? 1u : 0u;
}

// ---------------- weight/x prep (unchanged layouts) ----------------
__global__ __launch_bounds__(256) void prep_pack(const void* __restrict__ x, const void* __restrict__ W0,
                                                 const void* __restrict__ b0, const void* __restrict__ W1,
                                                 const void* __restrict__ b1, const void* __restrict__ Wout,
                                                 const void* __restrict__ bout, char* __restrict__ ws) {
  const int fl = *(const unsigned*)(ws + OFF_FLAG);
  int id = blockIdx.x * 256 + threadIdx.x;
  if (id < 5242880) {                                    // W0P
    int tile = id / 20480, rem = id % 20480;
    int kt = rem >> 9, l = (rem >> 3) & 63, jj = rem & 7;
    int k = kt * 32 + ((l >> 4) << 3) + jj;
    int pc = tile * 16 + (l & 15);
    ((bf16*)(ws + OFF_W0P))[id] = (bf16)ldel(W0, (size_t)k * 4096 + (pc & 3) * 1024 + (pc >> 2), fl);
  } else if (id < 13631488) {                            // W1P
    int id2 = id - 5242880;
    int tile = id2 >> 15, rem = id2 & 32767;
    int kt = rem >> 9, l = (rem >> 3) & 63, jj = rem & 7;
    int k = kt * 32 + ((l >> 4) << 3) + jj;
    int pc = tile * 16 + (l & 15);
    ((bf16*)(ws + OFF_W1P))[id2] = (bf16)ldel(W1, (size_t)k * 4096 + (pc & 3) * 1024 + (pc >> 2), fl);
  } else if (id < 13893632) {                            // WOUT
    int id2 = id - 13631488;
    int kt = id2 / 8192, rem = id2 % 8192;
    int nt = rem >> 9, l = (rem >> 3) & 63, jj = rem & 7;
    ((bf16*)(ws + OFF_WOUT))[id2] = (bf16)ldel(Wout, (size_t)(kt * 32 + ((l >> 4) << 3) + jj) * 256 + nt * 16 + (l & 15), fl);
  } else if (id < 13897728) {                            // b0 permuted -> f32
    int pc = id - 13893632;
    ((float*)(ws + OFF_B0P))[pc] = ldel(b0, (pc & 3) * 1024 + (pc >> 2), fl);
  } else if (id < 13901824) {                            // b1 permuted -> f32
    int pc = id - 13897728;
    ((float*)(ws + OFF_B1P))[pc] = ldel(b1, (pc & 3) * 1024 + (pc >> 2), fl);
  } else if (id < 13902080) {                            // bout -> f32
    int pc = id - 13901824;
    ((float*)(ws + OFF_BOP))[pc] = ldel(bout, pc, fl);
  } else if (id < 22290688) {                            // XP
    int id2 = id - 13902080;
    int t = id2 >> 14, rem = id2 & 16383;
    int mt = rem >> 12, rem2 = rem & 4095;
    int kt = rem2 >> 9, l = (rem2 >> 3) & 63, j = rem2 & 7;
    int b = mt * 16 + (l & 15);
    int v = kt * 32 + ((l >> 4) << 3) + j;
    ((bf16*)(ws + OFF_XP))[id2] = (bf16)ldel(x, ((size_t)b * 512 + t) * 256 + v, fl);
  }
}

// ---------------- initial h states + zero barrier flags ----------------
__global__ __launch_bounds__(256) void init_state(const void* __restrict__ s0, const void* __restrict__ s1,
                                                  char* __restrict__ ws) {
  const int fl = *(const unsigned*)(ws + OFF_FLAG);
  int id = blockIdx.x * 256 + threadIdx.x;
  if (id < 65536) {
    int b = id >> 10, u = id & 1023;
    *(bf16*)(ws + OFF_H0PP + 131072 + hpack_off(b, u)) = (bf16)ldel(s0, b * 2048 + 1024 + u, fl);
  } else if (id < 131072) {
    int id2 = id - 65536; int b = id2 >> 10, u = id2 & 1023;
    *(bf16*)(ws + OFF_H1PP + hpack_off(b, u)) = (bf16)ldel(s1, b * 2048 + 1024 + u, fl);
  } else if (id < 131329) {
    ((unsigned*)(ws + OFF_FLAGS))[id - 131072] = 0u;
  }
}

// ---------------- persistent kernel: recurrence + fused output projection ----------------
// 256 WGs x 512 threads (8 waves), 1 WG/CU -> 2 waves/SIMD.
// LDS: B0 [0,40960); B1 [40960,106496); outproj scratch [106496,110592).
// Layer-split waves:
//   wid 0..3 (m = wid):   acc0 = [x(it)||h0(it-1)] @ W0tile (40 loads, 40 MFMA) + layer-0
//                         epilogue + fused outproj (8 MFMA, 4-partial LDS reduce)
//   wid 4..7 (m = wid-4): acc1 = [h0(it-1)||h1(it-2)] @ W1tile (64 loads, 64 MFMA) + layer-1 epilogue
// A-frags streamed per-wave through a 16-deep register ring (no A-LDS, no barriers in GEMM).
// Grid sync: per-CU arrival flag; ALL threads poll flags[tid&255] (one L3 hop, no CU0 aggregate).
__global__ __launch_bounds__(512, 2) void recur_kernel(const void* __restrict__ s0, const void* __restrict__ s1,
                                                       char* __restrict__ ws, void* __restrict__ outv) {
  extern __shared__ char smem[];
  const int fl = *(const unsigned*)(ws + OFF_FLAG);
  const int tid = threadIdx.x;
  const int lane = tid & 63;
  const int wid = tid >> 6;       // 0..7
  const int half1w = (wid >= 4);
  const int m = wid & 3;          // m-tile for this wave's GEMM
  const int cu = blockIdx.x;
  const int nt = cu & 15, mo = (cu >> 4) & 3, dg = cu >> 6;

  auto store_out = [&](size_t idx, float v) {
    if (fl) ((float*)outv)[idx] = v; else ((bf16*)outv)[idx] = (bf16)v;
  };

  // ---- B preload (once) ----
  {
    const char* g0 = ws + OFF_W0P + (size_t)cu * 40960;
    for (int off = tid * 16; off < 40960; off += 8192) gl_lds16(smem + off, g0 + off);
    const char* g1 = ws + OFF_W1P + (size_t)cu * 65536;
    for (int off = tid * 16; off < 65536; off += 8192) gl_lds16(smem + 40960 + off, g1 + off);
  }
  // ---- Wout B-frags in registers (half0 waves own outproj k-tiles m*8..m*8+7) ----
  bf16x8 wreg[8];
  if (!half1w) {
#pragma unroll
    for (int i = 0; i < 8; ++i)
      wreg[i] = *(const bf16x8*)(ws + OFF_WOUT + (size_t)(((m * 8 + i) * 16 + nt) * 64 + lane) * 16);
  }

  const float bini0 = ((const float*)(ws + OFF_B0P))[cu * 16 + (lane & 15)];
  const float bini1 = ((const float*)(ws + OFF_B1P))[cu * 16 + (lane & 15)];
  const float boN = ((const float*)(ws + OFF_BOP))[nt * 16 + (lane & 15)];
  const int u0 = cu * 4 + ((lane & 15) >> 2);
  const int brow = m * 16 + ((lane >> 4) << 2);
  float creg[4];
#pragma unroll
  for (int r = 0; r < 4; ++r)
    creg[r] = ldel(half1w ? s1 : s0, (brow + r) * 2048 + u0, fl);

  unsigned* flags = (unsigned*)(ws + OFF_FLAGS);
  const char* dummy = ws + (size_t)lane * 16;          // W0P region: always-valid bf16
  const char* lb0 = smem + (size_t)lane * 16;          // B0 frag base (+ s*1024 imm)
  const char* lb1 = smem + 40960 + (size_t)lane * 16;  // B1 frag base (+ (s-8)*1024 imm)

  __syncthreads();  // B preload landed (compiler drains vmcnt before barrier)

  for (int it = 0; it < 514; ++it) {
    const bool a0 = (it < 512);
    const bool a1 = (it >= 1 && it <= 512);
    const bool aP = (it >= 2 && ((it - 2) & 3) == dg);
    const char* h0src = ws + OFF_H0PP + (size_t)((it + 1) & 1) * 131072;   // h0(it-1)
    const char* h1src = ws + OFF_H1PP + (size_t)((it + 1) & 1) * 131072;   // h1(it-2)

    f32x4 acc, accP;
#pragma unroll
    for (int r = 0; r < 4; ++r) { acc[r] = half1w ? bini1 : bini0; accP[r] = 0.f; }

    if (!half1w) {
      // ---- layer-0 GEMM: s = 0..39 (x 8 + h0 32) ----
      const char* px  = a0 ? (ws + OFF_XP + (size_t)((it * 4 + m) * 8) * 1024 + (size_t)lane * 16) : dummy;
      const char* ph0 = (it <= 512) ? (h0src + (size_t)(m * 32) * 1024 + (size_t)lane * 16) : dummy;
      // outproj A-frags issued earliest (overlap whole GEMM)
      bf16x8 pf[8];
      if (aP) {
        const char* pm = h1src + (size_t)(mo * 32 + m * 8) * 1024 + (size_t)lane * 16;
#pragma unroll
        for (int q = 0; q < 8; ++q) pf[q] = *(const bf16x8*)(pm + q * 1024);
      }
      bf16x8 ring[16];
#pragma unroll
      for (int s = 0; s < 16; ++s)
        ring[s] = *(const bf16x8*)(s < 8 ? px + s * 1024 : ph0 + (s - 8) * 1024);
#pragma unroll
      for (int s = 0; s < 40; ++s) {
        bf16x8 af = ring[s % 16];
        const int t2 = s + 16;
        if (t2 < 40)
          ring[s % 16] = *(const bf16x8*)(t2 < 8 ? px + t2 * 1024 : ph0 + (t2 - 8) * 1024);
        acc = __builtin_amdgcn_mfma_f32_16x16x32_bf16(af, *(const bf16x8*)(lb0 + s * 1024), acc, 0, 0, 0);
      }
      if (aP) {
#pragma unroll
        for (int q = 0; q < 8; ++q)
          accP = __builtin_amdgcn_mfma_f32_16x16x32_bf16(pf[q], wreg[q], accP, 0, 0, 0);
      }
    } else {
      // ---- layer-1 GEMM: s = 8..71 (h0 32 + h1 32) ----
      const char* ph0 = (it <= 512) ? (h0src + (size_t)(m * 32) * 1024 + (size_t)lane * 16) : dummy;
      const char* ph1 = a1 ? (h1src + (size_t)(m * 32) * 1024 + (size_t)lane * 16) : dummy;
      bf16x8 ring[16];
#pragma unroll
      for (int s = 8; s < 24; ++s)
        ring[(s - 8) % 16] = *(const bf16x8*)(ph0 + (s - 8) * 1024);
#pragma unroll
      for (int s = 8; s < 72; ++s) {
        bf16x8 af = ring[(s - 8) % 16];
        const int t2 = s + 16;
        if (t2 < 72)
          ring[(s - 8) % 16] = *(const bf16x8*)(t2 < 40 ? ph0 + (t2 - 8) * 1024 : ph1 + (t2 - 40) * 1024);
        acc = __builtin_amdgcn_mfma_f32_16x16x32_bf16(af, *(const bf16x8*)(lb1 + (s - 8) * 1024), acc, 0, 0, 0);
      }
    }

    // ---- LSTM epilogues (half0: layer0; half1: layer1 — concurrent on different waves) ----
    const int base = lane & 60;
    const bool act = half1w ? a1 : a0;
    if (act) {
      char* hw = ws + (half1w ? OFF_H1PP : OFF_H0PP) + (size_t)(it & 1) * 131072;
      const int itFS = half1w ? 512 : 511;
      const int outFS = half1w ? OUT_FS1 : OUT_FS0;
#pragma unroll
      for (int r = 0; r < 4; ++r) {
        float z = acc[r];
        float zi = scrub(__shfl(z, base + 0, 64), 80.f);
        float zj = scrub(__shfl(z, base + 1, 64), 80.f);
        float zf = scrub(__shfl(z, base + 2, 64), 80.f);
        float zo = scrub(__shfl(z, base + 3, 64), 80.f);
        float c = creg[r];
        c = c * sigm(zf + 1.0f) + sigm(zi) * tanh_(zj);
        c = scrub(c, 1000.f);
        float h = tanh_(c) * sigm(zo);
        creg[r] = c;
        if ((lane & 3) == 0) {
          int b = brow + r;
          *(bf16*)(hw + hpack_off(b, u0)) = (bf16)h;
          if (it == itFS) { store_out(outFS + b * 2048 + u0, c); store_out(outFS + b * 2048 + 1024 + u0, h); }
        }
      }
    }
    // ---- fused outproj: 4 half0 partials -> LDS reduce -> write out[:, it-2, nt-tile] ----
    if (aP) {
      if (!half1w)
        *(f32x4*)(smem + 106496 + (size_t)(m * 64 + lane) * 16) = accP;
      __syncthreads();
      if (wid == 0) {
        f32x4 sm = *(const f32x4*)(smem + 106496 + (size_t)lane * 16);
#pragma unroll
        for (int w = 1; w < 4; ++w) {
          f32x4 p = *(const f32x4*)(smem + 106496 + (size_t)(w * 64 + lane) * 16);
#pragma unroll
          for (int r = 0; r < 4; ++r) sm[r] += p[r];
        }
        int t = it - 2;
#pragma unroll
        for (int r = 0; r < 4; ++r) {
          int b = mo * 16 + ((lane >> 4) << 2) + r;
          store_out(((size_t)b * 512 + t) * 256 + nt * 16 + (lane & 15), sm[r] + boN);
        }
      }
    }

    // ---- grid barrier: arrive (release) -> all threads poll all flags -> acquire ----
    __syncthreads();
    if (tid == 0) {
      __builtin_amdgcn_fence(__ATOMIC_RELEASE, "agent");   // L2 writeback: h stores visible at L3
      __hip_atomic_store(flags + cu, (unsigned)(it + 1), __ATOMIC_RELAXED, __HIP_MEMORY_SCOPE_AGENT);
    }
    {
      const unsigned tgt = (unsigned)(it + 1);
      while (__hip_atomic_load(flags + (tid & 255), __ATOMIC_RELAXED, __HIP_MEMORY_SCOPE_AGENT) < tgt)
        __builtin_amdgcn_s_sleep(2);
    }
    __syncthreads();
    if (tid == 0)
      __builtin_amdgcn_fence(__ATOMIC_ACQUIRE, "agent");   // L1/L2 invalidate: see fresh h
    __syncthreads();
  }
}

extern "C" void kernel_launch(void* const* d_in, const int* in_sizes, int n_in,
                              void* d_out, int out_size, void* d_ws, size_t ws_size,
                              hipStream_t stream) {
  const void* x    = d_in[0];
  const void* s0   = d_in[1];
  const void* s1   = d_in[2];
  const void* W0   = d_in[3];
  const void* b0   = d_in[4];
  const void* W1   = d_in[5];
  const void* b1   = d_in[6];
  const void* Wout = d_in[7];
  const void* bout = d_in[8];
  char* ws = (char*)d_ws;
  (void)in_sizes; (void)n_in; (void)out_size; (void)ws_size;

  hipFuncSetAttribute((const void*)recur_kernel, hipFuncAttributeMaxDynamicSharedMemorySize, 110592);

  hipLaunchKernelGGL(detect_kernel, dim3(1),     dim3(256), 0, stream, W0, ws);
  hipLaunchKernelGGL(prep_pack,     dim3(87073), dim3(256), 0, stream, x, W0, b0, W1, b1, Wout, bout, ws);
  hipLaunchKernelGGL(init_state,    dim3(514),   dim3(256), 0, stream, s0, s1, ws);
  hipLaunchKernelGGL(recur_kernel,  dim3(256),   dim3(512), 110592, stream, s0, s1, ws, d_out);
}

// Round 3
// 7099.573 us; speedup vs baseline: 1.1904x; 1.1904x over previous
//
#include <hip/hip_runtime.h>
#include <stdint.h>

typedef __bf16 bf16;
typedef __attribute__((ext_vector_type(8))) __bf16 bf16x8;
typedef __attribute__((ext_vector_type(4))) float f32x4;

// ---------------- workspace layout (bytes) ----------------
//   W0P: [tile 256][kt 40][lane 64][8 bf16]   (K=1280: x rows 0..255, h0 rows 256..1279)
//   W1P: [tile 256][kt 64][lane 64][8 bf16]   (K=2048: h0 rows 0..1023, h1 rows 1024..2047)
//   WOUT:[kt 32][nt 16][lane 64][8 bf16]      (K=1024, N=256)
//   XP:  [t 512][mt 4][kt 8][lane 64][8 bf16] (x repacked into A-frag order, always bf16)
//   FLAGS: 256 x u32 per-CU arrival flags + release word
#define OFF_W0P   0ull
#define SZ_W0P    10485760ull
#define OFF_W1P   (OFF_W0P + SZ_W0P)
#define SZ_W1P    16777216ull
#define OFF_WOUT  (OFF_W1P + SZ_W1P)
#define SZ_WOUT   524288ull
#define OFF_B0P   (OFF_WOUT + SZ_WOUT)      // f32 permuted b0 [4096]
#define OFF_B1P   (OFF_B0P + 16384ull)      // f32 permuted b1 [4096]
#define OFF_BOP   (OFF_B1P + 16384ull)      // f32 bout [256]
#define OFF_BAR   (OFF_BOP + 1024ull)       // (legacy, unused)
#define OFF_FLAG  (OFF_BAR + 128ull)        // dtype flag: 1 = inputs are f32, 0 = bf16
#define OFF_H0PP  (OFF_BAR + 256ull)        // h0 ping-pong: 2 x 131072 (A-frag packed bf16)
#define OFF_H1PP  (OFF_H0PP + 262144ull)    // h1 ping-pong: 2 x 131072
#define OFF_XP    (OFF_H1PP + 262144ull)
#define SZ_XP     16777216ull
#define OFF_FLAGS (OFF_XP + SZ_XP)          // 256 x u32 arrival flags (1 KB)
#define OFF_REL   (OFF_FLAGS + 1024ull)     // release word, own line
// end = 45,123,968 bytes

#define OUT_FS0   8388608                   // final_state fs0 base (elements in d_out)
#define OUT_FS1   8519680                   // fs1 base

// LDS partial-exchange scratch (bytes, on top of B0 [0,40960) + B1 [40960,106496))
#define LDS_PART0 106496                    // acc0 partials from B-side waves (4 KB)
#define LDS_PART1 110592                    // acc1 partials from A-side waves (4 KB)
#define LDS_PARTP 114688                    // outproj partials from B-side waves (4 KB)
#define LDS_TOTAL 118784

typedef const __attribute__((address_space(1))) void gvoid_t;
typedef __attribute__((address_space(3))) void lvoid_t;

__device__ __forceinline__ void gl_lds16(void* lds, const void* g) {
  __builtin_amdgcn_global_load_lds((gvoid_t*)g, (lvoid_t*)lds, 16, 0, 0);
}

// packed A-fragment byte offset for h buffers: element (batch b, unit u)
__device__ __forceinline__ size_t hpack_off(int b, int u) {
  return (size_t)((((b >> 4) * 32 + (u >> 5)) * 64 + ((b & 15) | (((u >> 3) & 3) << 4))) * 16 + ((u & 7) << 1));
}

__device__ __forceinline__ float sigm(float v) { return 1.0f / (1.0f + __expf(-v)); }
__device__ __forceinline__ float tanh_(float v) { return 2.0f / (1.0f + __expf(-2.0f * v)) - 1.0f; }
__device__ __forceinline__ float scrub(float v, float lim) { return fminf(fmaxf(v, -lim), lim); }

__device__ __forceinline__ float ldel(const void* p, size_t i, int fl) {
  return fl ? ((const float*)p)[i] : (float)((const bf16*)p)[i];
}

// ---------------- dtype detection ----------------
__global__ __launch_bounds__(256) void detect_kernel(const void* __restrict__ W0, char* __restrict__ ws) {
  __shared__ int cnt;
  if (threadIdx.x == 0) cnt = 0;
  __syncthreads();
  int local = 0;
  const unsigned* w = (const unsigned*)W0;
#pragma unroll
  for (int i = 0; i < 4; ++i) {
    unsigned e = (w[threadIdx.x * 4 + i] >> 7) & 0xFF;
    local += (e >= 0x68 && e <= 0x7E) ? 1 : 0;
  }
  atomicAdd(&cnt, local);
  __syncthreads();
  if (threadIdx.x == 0) *(unsigned*)(ws + OFF_FLAG) = (cnt < 512) ? 1u : 0u;
}

// ---------------- weight/x prep (unchanged layouts) ----------------
__global__ __launch_bounds__(256) void prep_pack(const void* __restrict__ x, const void* __restrict__ W0,
                                                 const void* __restrict__ b0, const void* __restrict__ W1,
                                                 const void* __restrict__ b1, const void* __restrict__ Wout,
                                                 const void* __restrict__ bout, char* __restrict__ ws) {
  const int fl = *(const unsigned*)(ws + OFF_FLAG);
  int id = blockIdx.x * 256 + threadIdx.x;
  if (id < 5242880) {                                    // W0P
    int tile = id / 20480, rem = id % 20480;
    int kt = rem >> 9, l = (rem >> 3) & 63, jj = rem & 7;
    int k = kt * 32 + ((l >> 4) << 3) + jj;
    int pc = tile * 16 + (l & 15);
    ((bf16*)(ws + OFF_W0P))[id] = (bf16)ldel(W0, (size_t)k * 4096 + (pc & 3) * 1024 + (pc >> 2), fl);
  } else if (id < 13631488) {                            // W1P
    int id2 = id - 5242880;
    int tile = id2 >> 15, rem = id2 & 32767;
    int kt = rem >> 9, l = (rem >> 3) & 63, jj = rem & 7;
    int k = kt * 32 + ((l >> 4) << 3) + jj;
    int pc = tile * 16 + (l & 15);
    ((bf16*)(ws + OFF_W1P))[id2] = (bf16)ldel(W1, (size_t)k * 4096 + (pc & 3) * 1024 + (pc >> 2), fl);
  } else if (id < 13893632) {                            // WOUT
    int id2 = id - 13631488;
    int kt = id2 / 8192, rem = id2 % 8192;
    int nt = rem >> 9, l = (rem >> 3) & 63, jj = rem & 7;
    ((bf16*)(ws + OFF_WOUT))[id2] = (bf16)ldel(Wout, (size_t)(kt * 32 + ((l >> 4) << 3) + jj) * 256 + nt * 16 + (l & 15), fl);
  } else if (id < 13897728) {                            // b0 permuted -> f32
    int pc = id - 13893632;
    ((float*)(ws + OFF_B0P))[pc] = ldel(b0, (pc & 3) * 1024 + (pc >> 2), fl);
  } else if (id < 13901824) {                            // b1 permuted -> f32
    int pc = id - 13897728;
    ((float*)(ws + OFF_B1P))[pc] = ldel(b1, (pc & 3) * 1024 + (pc >> 2), fl);
  } else if (id < 13902080) {                            // bout -> f32
    int pc = id - 13901824;
    ((float*)(ws + OFF_BOP))[pc] = ldel(bout, pc, fl);
  } else if (id < 22290688) {                            // XP
    int id2 = id - 13902080;
    int t = id2 >> 14, rem = id2 & 16383;
    int mt = rem >> 12, rem2 = rem & 4095;
    int kt = rem2 >> 9, l = (rem2 >> 3) & 63, j = rem2 & 7;
    int b = mt * 16 + (l & 15);
    int v = kt * 32 + ((l >> 4) << 3) + j;
    ((bf16*)(ws + OFF_XP))[id2] = (bf16)ldel(x, ((size_t)b * 512 + t) * 256 + v, fl);
  }
}

// ---------------- initial h states + zero barrier flags ----------------
__global__ __launch_bounds__(256) void init_state(const void* __restrict__ s0, const void* __restrict__ s1,
                                                  char* __restrict__ ws) {
  const int fl = *(const unsigned*)(ws + OFF_FLAG);
  int id = blockIdx.x * 256 + threadIdx.x;
  if (id < 65536) {
    int b = id >> 10, u = id & 1023;
    *(bf16*)(ws + OFF_H0PP + 131072 + hpack_off(b, u)) = (bf16)ldel(s0, b * 2048 + 1024 + u, fl);
  } else if (id < 131072) {
    int id2 = id - 65536; int b = id2 >> 10, u = id2 & 1023;
    *(bf16*)(ws + OFF_H1PP + hpack_off(b, u)) = (bf16)ldel(s1, b * 2048 + 1024 + u, fl);
  } else if (id < 131330) {
    ((unsigned*)(ws + OFF_FLAGS))[id - 131072] = 0u;   // 256 flags + release word
  }
}

// ---------------- persistent kernel: recurrence + fused output projection ----------------
// 256 WGs x 512 threads (8 waves), 1 WG/CU -> 2 waves/SIMD.
// K-SPLIT pairing (same traffic as the 4-wave version, unlike the layer-split):
//   wave pair (m, m+4) shares m-tile m; h0 frags still feed BOTH acc0 and acc1 (2 MFMA/frag).
//   A-side (wid 0..3,  m=wid):  loads x 0..7 + h0 0..15 + h1 0..15  (40); MFMA acc0 24 + acc1 32
//   B-side (wid 4..7, m=wid-4): loads h0 16..31 + h1 16..31 (32, +8 pf); MFMA acc0 16 + acc1 32 (+8 outP)
// Partial exchange via LDS (A gets B's acc0; B gets A's acc1), then CONCURRENT epilogues:
//   A-side: layer-0 epilogue; B-side: layer-1 epilogue; outproj reduce spread over 4 A-waves.
// Grid sync: per-CU flag -> CU0 aggregates -> release word (R1's measured-good design).
__global__ __launch_bounds__(512, 2) void recur_kernel(const void* __restrict__ s0, const void* __restrict__ s1,
                                                       char* __restrict__ ws, void* __restrict__ outv) {
  extern __shared__ char smem[];
  const int fl = *(const unsigned*)(ws + OFF_FLAG);
  const int tid = threadIdx.x;
  const int lane = tid & 63;
  const int wid = tid >> 6;       // 0..7
  const int hi = wid >> 2;        // 0 = A-side, 1 = B-side
  const int m = wid & 3;          // m-tile of this wave pair
  const int cu = blockIdx.x;
  const int nt = cu & 15, mo = (cu >> 4) & 3, dg = cu >> 6;

  auto store_out = [&](size_t idx, float v) {
    if (fl) ((float*)outv)[idx] = v; else ((bf16*)outv)[idx] = (bf16)v;
  };

  // ---- B preload (once) ----
  {
    const char* g0 = ws + OFF_W0P + (size_t)cu * 40960;
    for (int off = tid * 16; off < 40960; off += 8192) gl_lds16(smem + off, g0 + off);
    const char* g1 = ws + OFF_W1P + (size_t)cu * 65536;
    for (int off = tid * 16; off < 65536; off += 8192) gl_lds16(smem + 40960 + off, g1 + off);
  }
  // ---- Wout B-frags in registers (B-side waves own outproj k-tiles m*8..m*8+7) ----
  bf16x8 wreg[8];
  if (hi) {
#pragma unroll
    for (int i = 0; i < 8; ++i)
      wreg[i] = *(const bf16x8*)(ws + OFF_WOUT + (size_t)(((m * 8 + i) * 16 + nt) * 64 + lane) * 16);
  }

  const float bini0 = ((const float*)(ws + OFF_B0P))[cu * 16 + (lane & 15)];
  const float bini1 = ((const float*)(ws + OFF_B1P))[cu * 16 + (lane & 15)];
  const float boN = ((const float*)(ws + OFF_BOP))[nt * 16 + (lane & 15)];
  const int u0 = cu * 4 + ((lane & 15) >> 2);
  const int brow = m * 16 + ((lane >> 4) << 2);
  float creg[4];
#pragma unroll
  for (int r = 0; r < 4; ++r)
    creg[r] = ldel(hi ? s1 : s0, (brow + r) * 2048 + u0, fl);   // A: c0, B: c1

  unsigned* flags = (unsigned*)(ws + OFF_FLAGS);
  unsigned* rel   = (unsigned*)(ws + OFF_REL);
  const char* dummy = ws + (size_t)lane * 16;          // W0P region: always-valid bf16
  const char* lb0 = smem + (size_t)lane * 16;          // B0 frag base (+ idx*1024 imm)
  const char* lb1 = smem + 40960 + (size_t)lane * 16;  // B1 frag base (+ idx*1024 imm)

  __syncthreads();  // B preload landed

  for (int it = 0; it < 514; ++it) {
    const bool a0 = (it < 512);
    const bool a1 = (it >= 1 && it <= 512);
    const bool aP = (it >= 2 && ((it - 2) & 3) == dg);
    const char* h0src = ws + OFF_H0PP + (size_t)((it + 1) & 1) * 131072;   // h0(it-1)
    const char* h1src = ws + OFF_H1PP + (size_t)((it + 1) & 1) * 131072;   // h1(it-2)

    f32x4 acc0, acc1, accP;
#pragma unroll
    for (int r = 0; r < 4; ++r) {
      acc0[r] = hi ? 0.f : bini0;    // bias counted exactly once across the pair
      acc1[r] = hi ? bini1 : 0.f;
      accP[r] = 0.f;
    }

    if (!hi) {
      // ---- A-side: x(8) + h0 frags 0..15 + h1 frags 0..15 ----
      const char* px  = a0 ? (ws + OFF_XP + (size_t)((it * 4 + m) * 8) * 1024 + (size_t)lane * 16) : dummy;
      const char* ph0 = (it <= 512) ? (h0src + (size_t)(m * 32) * 1024 + (size_t)lane * 16) : dummy;
      const char* ph1 = a1 ? (h1src + (size_t)(m * 32) * 1024 + (size_t)lane * 16) : dummy;
      bf16x8 ring[16];
#pragma unroll
      for (int s = 0; s < 16; ++s)
        ring[s] = *(const bf16x8*)(s < 8 ? px + s * 1024 : ph0 + (s - 8) * 1024);
#pragma unroll
      for (int s = 0; s < 40; ++s) {
        bf16x8 af = ring[s & 15];
        const int t2 = s + 16;
        if (t2 < 40)
          ring[s & 15] = *(const bf16x8*)(t2 < 24 ? ph0 + (t2 - 8) * 1024 : ph1 + (t2 - 24) * 1024);
        if (s < 8) {
          if (a0) acc0 = __builtin_amdgcn_mfma_f32_16x16x32_bf16(af, *(const bf16x8*)(lb0 + s * 1024), acc0, 0, 0, 0);
        } else if (s < 24) {
          if (a0) acc0 = __builtin_amdgcn_mfma_f32_16x16x32_bf16(af, *(const bf16x8*)(lb0 + s * 1024), acc0, 0, 0, 0);
          if (a1) acc1 = __builtin_amdgcn_mfma_f32_16x16x32_bf16(af, *(const bf16x8*)(lb1 + (s - 8) * 1024), acc1, 0, 0, 0);
        } else {
          if (a1) acc1 = __builtin_amdgcn_mfma_f32_16x16x32_bf16(af, *(const bf16x8*)(lb1 + (s + 8) * 1024), acc1, 0, 0, 0);
        }
      }
    } else {
      // ---- B-side: h0 frags 16..31 + h1 frags 16..31 (+ outproj pf) ----
      const char* ph0 = (it <= 512) ? (h0src + (size_t)(m * 32 + 16) * 1024 + (size_t)lane * 16) : dummy;
      const char* ph1 = a1 ? (h1src + (size_t)(m * 32 + 16) * 1024 + (size_t)lane * 16) : dummy;
      bf16x8 pf[8];
      if (aP) {
        const char* pm = h1src + (size_t)(mo * 32 + m * 8) * 1024 + (size_t)lane * 16;
#pragma unroll
        for (int q = 0; q < 8; ++q) pf[q] = *(const bf16x8*)(pm + q * 1024);
      }
      bf16x8 ring[16];
#pragma unroll
      for (int s = 0; s < 16; ++s)
        ring[s] = *(const bf16x8*)(ph0 + s * 1024);
#pragma unroll
      for (int s = 0; s < 32; ++s) {
        bf16x8 af = ring[s & 15];
        const int t2 = s + 16;
        if (t2 < 32)
          ring[s & 15] = *(const bf16x8*)(ph1 + (t2 - 16) * 1024);
        if (s < 16) {
          if (a0) acc0 = __builtin_amdgcn_mfma_f32_16x16x32_bf16(af, *(const bf16x8*)(lb0 + (24 + s) * 1024), acc0, 0, 0, 0);
          if (a1) acc1 = __builtin_amdgcn_mfma_f32_16x16x32_bf16(af, *(const bf16x8*)(lb1 + (16 + s) * 1024), acc1, 0, 0, 0);
        } else {
          if (a1) acc1 = __builtin_amdgcn_mfma_f32_16x16x32_bf16(af, *(const bf16x8*)(lb1 + (32 + s) * 1024), acc1, 0, 0, 0);
        }
      }
      if (aP) {
#pragma unroll
        for (int q = 0; q < 8; ++q)
          accP = __builtin_amdgcn_mfma_f32_16x16x32_bf16(pf[q], wreg[q], accP, 0, 0, 0);
      }
    }

    // ---- partial exchange: A gives acc1, B gives acc0 (and accP) ----
    if (!hi) {
      *(f32x4*)(smem + LDS_PART1 + (size_t)(m * 64 + lane) * 16) = acc1;
    } else {
      *(f32x4*)(smem + LDS_PART0 + (size_t)(m * 64 + lane) * 16) = acc0;
      if (aP) *(f32x4*)(smem + LDS_PARTP + (size_t)(m * 64 + lane) * 16) = accP;
    }
    __syncthreads();

    f32x4 accT;
    if (!hi) {
      f32x4 p = *(const f32x4*)(smem + LDS_PART0 + (size_t)(m * 64 + lane) * 16);
#pragma unroll
      for (int r = 0; r < 4; ++r) accT[r] = acc0[r] + p[r];
    } else {
      f32x4 p = *(const f32x4*)(smem + LDS_PART1 + (size_t)(m * 64 + lane) * 16);
#pragma unroll
      for (int r = 0; r < 4; ++r) accT[r] = acc1[r] + p[r];
    }

    // ---- LSTM epilogues (A: layer-0, B: layer-1 — concurrent on different waves) ----
    const int base = lane & 60;
    const bool act = hi ? a1 : a0;
    if (act) {
      char* hw = ws + (hi ? OFF_H1PP : OFF_H0PP) + (size_t)(it & 1) * 131072;
      const int itFS = hi ? 512 : 511;
      const int outFS = hi ? OUT_FS1 : OUT_FS0;
#pragma unroll
      for (int r = 0; r < 4; ++r) {
        float z = accT[r];
        float zi = scrub(__shfl(z, base + 0, 64), 80.f);
        float zj = scrub(__shfl(z, base + 1, 64), 80.f);
        float zf = scrub(__shfl(z, base + 2, 64), 80.f);
        float zo = scrub(__shfl(z, base + 3, 64), 80.f);
        float c = creg[r];
        c = c * sigm(zf + 1.0f) + sigm(zi) * tanh_(zj);
        c = scrub(c, 1000.f);
        float h = tanh_(c) * sigm(zo);
        creg[r] = c;
        if ((lane & 3) == 0) {
          int b = brow + r;
          *(bf16*)(hw + hpack_off(b, u0)) = (bf16)h;
          if (it == itFS) { store_out(outFS + b * 2048 + u0, c); store_out(outFS + b * 2048 + 1024 + u0, h); }
        }
      }
    }
    // ---- outproj reduce spread across the 4 A-side waves (wave m handles row r=m) ----
    if (aP && !hi) {
      float sm = 0.f;
#pragma unroll
      for (int p = 0; p < 4; ++p)
        sm += *(const float*)(smem + LDS_PARTP + (size_t)(p * 64 + lane) * 16 + m * 4);
      int t = it - 2;
      int b = mo * 16 + ((lane >> 4) << 2) + m;
      store_out(((size_t)b * 512 + t) * 256 + nt * 16 + (lane & 15), sm + boN);
    }

    // ---- grid barrier: flags -> CU0 aggregate -> release (R1 design) ----
    __syncthreads();
    if (tid == 0) {
      __builtin_amdgcn_fence(__ATOMIC_RELEASE, "agent");   // L2 writeback: h stores visible at L3
      __hip_atomic_store(flags + cu, (unsigned)(it + 1), __ATOMIC_RELAXED, __HIP_MEMORY_SCOPE_AGENT);
    }
    if (cu == 0) {
      if (tid < 256) {
        while (__hip_atomic_load(flags + tid, __ATOMIC_RELAXED, __HIP_MEMORY_SCOPE_AGENT) < (unsigned)(it + 1))
          __builtin_amdgcn_s_sleep(2);
      }
      __syncthreads();
      if (tid == 0)
        __hip_atomic_store(rel, (unsigned)(it + 1), __ATOMIC_RELAXED, __HIP_MEMORY_SCOPE_AGENT);
    }
    if (tid == 0) {
      while (__hip_atomic_load(rel, __ATOMIC_RELAXED, __HIP_MEMORY_SCOPE_AGENT) < (unsigned)(it + 1))
        __builtin_amdgcn_s_sleep(2);
      __builtin_amdgcn_fence(__ATOMIC_ACQUIRE, "agent");   // L1/L2 invalidate: see fresh h
    }
    __syncthreads();
  }
}

extern "C" void kernel_launch(void* const* d_in, const int* in_sizes, int n_in,
                              void* d_out, int out_size, void* d_ws, size_t ws_size,
                              hipStream_t stream) {
  const void* x    = d_in[0];
  const void* s0   = d_in[1];
  const void* s1   = d_in[2];
  const void* W0   = d_in[3];
  const void* b0   = d_in[4];
  const void* W1   = d_in[5];
  const void* b1   = d_in[6];
  const void* Wout = d_in[7];
  const void* bout = d_in[8];
  char* ws = (char*)d_ws;
  (void)in_sizes; (void)n_in; (void)out_size; (void)ws_size;

  hipFuncSetAttribute((const void*)recur_kernel, hipFuncAttributeMaxDynamicSharedMemorySize, LDS_TOTAL);

  hipLaunchKernelGGL(detect_kernel, dim3(1),     dim3(256), 0, stream, W0, ws);
  hipLaunchKernelGGL(prep_pack,     dim3(87073), dim3(256), 0, stream, x, W0, b0, W1, b1, Wout, bout, ws);
  hipLaunchKernelGGL(init_state,    dim3(514),   dim3(256), 0, stream, s0, s1, ws);
  hipLaunchKernelGGL(recur_kernel,  dim3(256),   dim3(512), LDS_TOTAL, stream, s0, s1, ws, d_out);
}